// Round 1
// 555.139 us; speedup vs baseline: 1.0470x; 1.0470x over previous
//
#include <hip/hip_runtime.h>

// MultiHeadSelfAttention: X(4,512,512) -> QKV via fused conv projections,
// fused scores+softmax+attn-write+P@V (one kernel), out proj.
// ws layout (floats): Q[1M] K[1M] V[1M] ctxp[8 x 1M] => 44 MB.

__device__ __forceinline__ void fma4(float4& a, float s, const float4& v) {
  a.x = fmaf(s, v.x, a.x);
  a.y = fmaf(s, v.y, a.y);
  a.z = fmaf(s, v.z, a.z);
  a.w = fmaf(s, v.w, a.w);
}

// ---------------------------------------------------------------------------
// Fused 2-layer conv projection: conv3x3(1->8)+BN+ReLU, conv3x3(8->1)+BN+ReLU.
// 32x32 output tile per block; y1 (34x34x8) lives in LDS only.
// nparts==8: input is sum of 8 partial buffers (ctx reduction fused here).
// ---------------------------------------------------------------------------
__global__ __launch_bounds__(256)
void conv_proj_kernel(const float* __restrict__ in, int nparts,
                      float* __restrict__ out, int fixed_proj,
                      const float* __restrict__ w1, const float* __restrict__ b1,
                      const float* __restrict__ g1, const float* __restrict__ be1,
                      const float* __restrict__ m1, const float* __restrict__ v1,
                      const float* __restrict__ w2, const float* __restrict__ b2,
                      const float* __restrict__ g2, const float* __restrict__ be2,
                      const float* __restrict__ m2, const float* __restrict__ v2)
{
  __shared__ float xs[36][36];
  __shared__ float ys[8][34][34];
  __shared__ float w1s[8][9];
  __shared__ float w2s[8][9];
  __shared__ float a1s[8], c1s[8];
  __shared__ float a2s[1], c2s[1];

  const int t = threadIdx.x;
  int proj, b;
  if (fixed_proj < 0) { proj = blockIdx.z >> 2; b = blockIdx.z & 3; }
  else                { proj = fixed_proj;      b = blockIdx.z;     }
  const int h0 = blockIdx.y * 32;
  const int w0 = blockIdx.x * 32;

  if (t < 72) {
    w1s[t / 9][t % 9] = w1[proj * 72 + t];
    w2s[t / 9][t % 9] = w2[proj * 72 + t];
  } else if (t < 80) {
    int ch = t - 72;
    float a = g1[proj * 8 + ch] * rsqrtf(v1[proj * 8 + ch] + 1e-5f);
    a1s[ch] = a;
    c1s[ch] = fmaf(a, b1[proj * 8 + ch] - m1[proj * 8 + ch], be1[proj * 8 + ch]);
  } else if (t == 80) {
    float a = g2[proj] * rsqrtf(v2[proj] + 1e-5f);
    a2s[0] = a;
    c2s[0] = fmaf(a, b2[proj] - m2[proj], be2[proj]);
  }

  for (int idx = t; idx < 36 * 36; idx += 256) {
    int r = idx / 36, c = idx - r * 36;
    int hg = h0 - 2 + r, wg = w0 - 2 + c;
    float val = 0.f;
    if (hg >= 0 && hg < 512 && wg >= 0 && wg < 512) {
      int off = b * 262144 + hg * 512 + wg;
      if (nparts == 1) {
        val = in[off];
      } else {
        #pragma unroll
        for (int p = 0; p < 8; ++p) val += in[p * 1048576 + off];
      }
    }
    xs[r][c] = val;
  }
  __syncthreads();

  for (int idx = t; idx < 34 * 34; idx += 256) {
    int r = idx / 34, c = idx - r * 34;
    int hg1 = h0 - 1 + r, wg1 = w0 - 1 + c;
    bool inside = (hg1 >= 0) & (hg1 < 512) & (wg1 >= 0) & (wg1 < 512);
    float x0 = xs[r    ][c], x1 = xs[r    ][c + 1], x2 = xs[r    ][c + 2];
    float x3 = xs[r + 1][c], x4 = xs[r + 1][c + 1], x5 = xs[r + 1][c + 2];
    float x6 = xs[r + 2][c], x7 = xs[r + 2][c + 1], x8 = xs[r + 2][c + 2];
    #pragma unroll
    for (int ch = 0; ch < 8; ++ch) {
      const float* w = w1s[ch];
      float acc = w[0] * x0 + w[1] * x1 + w[2] * x2
                + w[3] * x3 + w[4] * x4 + w[5] * x5
                + w[6] * x6 + w[7] * x7 + w[8] * x8;
      float y = fmaxf(fmaf(acc, a1s[ch], c1s[ch]), 0.f);
      ys[ch][r][c] = inside ? y : 0.f;
    }
  }
  __syncthreads();

  const int r0 = (t >> 4) * 2;
  const int c0 = (t & 15) * 2;
  float o00 = 0.f, o01 = 0.f, o10 = 0.f, o11 = 0.f;
  #pragma unroll
  for (int ch = 0; ch < 8; ++ch) {
    float win[4][4];
    #pragma unroll
    for (int rr = 0; rr < 4; ++rr) {
      float2 p0 = *(const float2*)&ys[ch][r0 + rr][c0];
      float2 p1 = *(const float2*)&ys[ch][r0 + rr][c0 + 2];
      win[rr][0] = p0.x; win[rr][1] = p0.y; win[rr][2] = p1.x; win[rr][3] = p1.y;
    }
    #pragma unroll
    for (int dh = 0; dh < 3; ++dh)
      #pragma unroll
      for (int dw = 0; dw < 3; ++dw) {
        float wgt = w2s[ch][dh * 3 + dw];
        o00 = fmaf(wgt, win[dh    ][dw    ], o00);
        o01 = fmaf(wgt, win[dh    ][dw + 1], o01);
        o10 = fmaf(wgt, win[dh + 1][dw    ], o10);
        o11 = fmaf(wgt, win[dh + 1][dw + 1], o11);
      }
  }
  const float a2 = a2s[0], cc2 = c2s[0];
  float2 row0 = make_float2(fmaxf(fmaf(o00, a2, cc2), 0.f),
                            fmaxf(fmaf(o01, a2, cc2), 0.f));
  float2 row1 = make_float2(fmaxf(fmaf(o10, a2, cc2), 0.f),
                            fmaxf(fmaf(o11, a2, cc2), 0.f));
  const int sel = (fixed_proj < 0) ? proj : 0;
  float* ob = out + sel * 1048576 + b * 262144;
  *(float2*)&ob[(h0 + r0    ) * 512 + (w0 + c0)] = row0;
  *(float2*)&ob[(h0 + r0 + 1) * 512 + (w0 + c0)] = row1;
}

// ---------------------------------------------------------------------------
// Fused attention: scores + softmax + attn write + P@V_j -> ctxp.
// Block = (m-tile of 32 queries, (i,j) head pair, b). 256 threads.
// Score phase: 32x512 S tile in registers (64/thread), K chunks (128 keys)
// transposed in LDS. Softmax per row over 32-lane groups. P stays in regs,
// gets normalized, written to attn, then spilled per-chunk into LDS for the
// P@V GEMM with V chunks staged beside it. Eliminates the separate ctx
// kernel and its 256 MB attn re-read.
// LDS: score phase qs[32][68] + kt[64][132] = 42.5 KB;
//      ctx phase   Pc[32][132] + Vc[128][68] = 51.7 KB (union) -> 3 blk/CU.
// ---------------------------------------------------------------------------
__global__ __launch_bounds__(256)
void attn_fused_kernel(const float* __restrict__ Q, const float* __restrict__ K,
                       const float* __restrict__ V,
                       float* __restrict__ attn, float* __restrict__ ctxp)
{
  __shared__ __align__(16) float smem[12928];
  float* qs = smem;          // [32][68]   score phase
  float* kt = smem + 2176;   // [64][132]  score phase
  float* Pc = smem;          // [32][132]  ctx phase (aliases qs/kt)
  float* Vc = smem + 4224;   // [128][68]  ctx phase

  const int t  = threadIdx.x;
  const int b  = blockIdx.z;
  const int ij = blockIdx.y;
  const int i  = ij >> 3, j = ij & 7;
  const int m0 = blockIdx.x * 32;

  const int tm = t >> 5;    // 0..7: rows tm + 8*mm
  const int tn = t & 31;    // 0..31: cols tn*4 within each 128-chunk

  // Stage Q tile (32x64), scaled by 1/sqrt(64).
  {
    int m = t >> 3, d0 = (t & 7) * 8;
    const float* qp = &Q[b * 262144 + (m0 + m) * 512 + i * 64 + d0];
    float4 qa = *(const float4*)qp;
    float4 qb = *(const float4*)(qp + 4);
    *(float4*)&qs[m * 68 + d0] =
        make_float4(qa.x * 0.125f, qa.y * 0.125f, qa.z * 0.125f, qa.w * 0.125f);
    *(float4*)&qs[m * 68 + d0 + 4] =
        make_float4(qb.x * 0.125f, qb.y * 0.125f, qb.z * 0.125f, qb.w * 0.125f);
  }

  float S[4][4][4];  // [chunk][row mm][col nn] — static indexing (unrolled)

  #pragma unroll
  for (int c = 0; c < 4; ++c) {
    __syncthreads();
    // Stage K chunk transposed: kt[d][n], n = c*128..c*128+127, d = 0..63.
    {
      int n = t >> 1, d0 = (t & 1) * 32;
      const float* kp = &K[b * 262144 + (c * 128 + n) * 512 + j * 64 + d0];
      #pragma unroll
      for (int q4 = 0; q4 < 8; ++q4) {
        float4 kv = *(const float4*)&kp[q4 * 4];
        kt[(d0 + q4 * 4 + 0) * 132 + n] = kv.x;
        kt[(d0 + q4 * 4 + 1) * 132 + n] = kv.y;
        kt[(d0 + q4 * 4 + 2) * 132 + n] = kv.z;
        kt[(d0 + q4 * 4 + 3) * 132 + n] = kv.w;
      }
    }
    __syncthreads();
    #pragma unroll
    for (int mm = 0; mm < 4; ++mm)
      #pragma unroll
      for (int nn = 0; nn < 4; ++nn) S[c][mm][nn] = 0.f;
    #pragma unroll 2
    for (int dd = 0; dd < 64; dd += 4) {
      float4 k0 = *(const float4*)&kt[(dd + 0) * 132 + tn * 4];
      float4 k1 = *(const float4*)&kt[(dd + 1) * 132 + tn * 4];
      float4 k2 = *(const float4*)&kt[(dd + 2) * 132 + tn * 4];
      float4 k3 = *(const float4*)&kt[(dd + 3) * 132 + tn * 4];
      #pragma unroll
      for (int mm = 0; mm < 4; ++mm) {
        float4 qv = *(const float4*)&qs[(tm + 8 * mm) * 68 + dd];
        S[c][mm][0] = fmaf(qv.x, k0.x, fmaf(qv.y, k1.x, fmaf(qv.z, k2.x, fmaf(qv.w, k3.x, S[c][mm][0]))));
        S[c][mm][1] = fmaf(qv.x, k0.y, fmaf(qv.y, k1.y, fmaf(qv.z, k2.y, fmaf(qv.w, k3.y, S[c][mm][1]))));
        S[c][mm][2] = fmaf(qv.x, k0.z, fmaf(qv.y, k1.z, fmaf(qv.z, k2.z, fmaf(qv.w, k3.z, S[c][mm][2]))));
        S[c][mm][3] = fmaf(qv.x, k0.w, fmaf(qv.y, k1.w, fmaf(qv.z, k2.w, fmaf(qv.w, k3.w, S[c][mm][3]))));
      }
    }
  }

  // Softmax per row (512 keys spread over the 32-lane tn group), write attn.
  // wave64: xor offsets 1..16 stay within each 32-lane half = the tn group.
  float* ap = attn + (size_t)((b * 8 + i) * 8 + j) * 262144;
  #pragma unroll
  for (int mm = 0; mm < 4; ++mm) {
    float mx = -3.0e38f;
    #pragma unroll
    for (int c = 0; c < 4; ++c)
      #pragma unroll
      for (int nn = 0; nn < 4; ++nn) mx = fmaxf(mx, S[c][mm][nn]);
    #pragma unroll
    for (int off = 1; off < 32; off <<= 1) mx = fmaxf(mx, __shfl_xor(mx, off));
    float sum = 0.f;
    #pragma unroll
    for (int c = 0; c < 4; ++c)
      #pragma unroll
      for (int nn = 0; nn < 4; ++nn) {
        float e = __expf(S[c][mm][nn] - mx);
        S[c][mm][nn] = e;
        sum += e;
      }
    #pragma unroll
    for (int off = 1; off < 32; off <<= 1) sum += __shfl_xor(sum, off);
    float rinv = 1.0f / sum;
    float* rowp = ap + (size_t)(m0 + tm + 8 * mm) * 512;
    #pragma unroll
    for (int c = 0; c < 4; ++c) {
      float4 o = make_float4(S[c][mm][0] * rinv, S[c][mm][1] * rinv,
                             S[c][mm][2] * rinv, S[c][mm][3] * rinv);
      S[c][mm][0] = o.x; S[c][mm][1] = o.y; S[c][mm][2] = o.z; S[c][mm][3] = o.w;
      *(float4*)&rowp[c * 128 + tn * 4] = o;
    }
  }

  // ctx phase: ctx[32][64] += P[32][128-chunk] @ V_chunk[128][64], 4 chunks.
  const int rp = t >> 4;        // 0..15 -> rows rp, rp+16
  const int cd = (t & 15) * 4;  // 0..60
  float4 acc0 = make_float4(0.f, 0.f, 0.f, 0.f);
  float4 acc1 = make_float4(0.f, 0.f, 0.f, 0.f);
  const float* vp = V + b * 262144 + j * 64;

  #pragma unroll
  for (int c = 0; c < 4; ++c) {
    __syncthreads();  // previous chunk GEMM reads done before Pc/Vc overwrite
    #pragma unroll
    for (int mm = 0; mm < 4; ++mm) {
      *(float4*)&Pc[(tm + 8 * mm) * 132 + tn * 4] =
          make_float4(S[c][mm][0], S[c][mm][1], S[c][mm][2], S[c][mm][3]);
    }
    {
      int k0 = t >> 4, d0 = (t & 15) * 4;
      #pragma unroll
      for (int q8 = 0; q8 < 8; ++q8) {
        int k = k0 + q8 * 16;
        *(float4*)&Vc[k * 68 + d0] =
            *(const float4*)&vp[(size_t)(c * 128 + k) * 512 + d0];
      }
    }
    __syncthreads();
    #pragma unroll 2
    for (int k = 0; k < 128; k += 4) {
      float4 pa = *(const float4*)&Pc[rp * 132 + k];
      float4 pb = *(const float4*)&Pc[(rp + 16) * 132 + k];
      float4 v0 = *(const float4*)&Vc[(k + 0) * 68 + cd];
      float4 v1 = *(const float4*)&Vc[(k + 1) * 68 + cd];
      float4 v2 = *(const float4*)&Vc[(k + 2) * 68 + cd];
      float4 v3 = *(const float4*)&Vc[(k + 3) * 68 + cd];
      fma4(acc0, pa.x, v0); fma4(acc0, pa.y, v1);
      fma4(acc0, pa.z, v2); fma4(acc0, pa.w, v3);
      fma4(acc1, pb.x, v0); fma4(acc1, pb.y, v1);
      fma4(acc1, pb.z, v2); fma4(acc1, pb.w, v3);
    }
  }
  float* op = ctxp + j * 1048576 + b * 262144 + i * 64 + cd;
  *(float4*)&op[(size_t)(m0 + rp)      * 512] = acc0;
  *(float4*)&op[(size_t)(m0 + rp + 16) * 512] = acc1;
}

extern "C" void kernel_launch(void* const* d_in, const int* in_sizes, int n_in,
                              void* d_out, int out_size, void* d_ws, size_t ws_size,
                              hipStream_t stream)
{
  const float* X   = (const float*)d_in[0];
  // d_in[1] = valid_lens: unused by the reference computation.
  const float* w1  = (const float*)d_in[2];
  const float* b1  = (const float*)d_in[3];
  const float* g1  = (const float*)d_in[4];
  const float* be1 = (const float*)d_in[5];
  const float* m1  = (const float*)d_in[6];
  const float* v1  = (const float*)d_in[7];
  const float* w2  = (const float*)d_in[8];
  const float* b2  = (const float*)d_in[9];
  const float* g2  = (const float*)d_in[10];
  const float* be2 = (const float*)d_in[11];
  const float* m2  = (const float*)d_in[12];
  const float* v2  = (const float*)d_in[13];

  float* ws   = (float*)d_ws;
  float* Qb   = ws;                  // 1M floats
  float* Kb   = ws + 1048576;        // 1M
  float* Vb   = ws + 2097152;        // 1M
  float* ctxp = ws + 3145728;        // 8 x 1M partials
  float* outp = (float*)d_out;       // out: 1,048,576 floats
  float* attn = outp + 1048576;      // attn: 67,108,864 floats

  // Q,K,V projections (proj 0..2 x b 0..3 in grid.z).
  conv_proj_kernel<<<dim3(16, 16, 12), 256, 0, stream>>>(
      X, 1, ws, -1, w1, b1, g1, be1, m1, v1, w2, b2, g2, be2, m2, v2);

  // Fused scores + softmax + attn write + P@V -> ctx partials (j-split).
  attn_fused_kernel<<<dim3(16, 64, 4), 256, 0, stream>>>(Qb, Kb, Vb, attn, ctxp);

  // Output projection (sums the 8 ctx partials during input staging).
  conv_proj_kernel<<<dim3(16, 16, 4), 256, 0, stream>>>(
      ctxp, 8, outp, 3, w1, b1, g1, be1, m1, v1, w2, b2, g2, be2, m2, v2);
}

// Round 2
// 469.785 us; speedup vs baseline: 1.2373x; 1.1817x over previous
//
#include <hip/hip_runtime.h>

// MultiHeadSelfAttention: X(4,512,512) -> QKV via fused conv projections,
// fused scores+softmax+attn-write+P@V (one kernel, PV on MFMA split-bf16),
// out proj.
// ws layout (floats): Q[1M] K[1M] VtH[0.5M] VtL[0.5M] ctxp[8 x 1M] => 44 MB.

typedef __bf16 bf16x8 __attribute__((ext_vector_type(8)));
typedef float  f32x4  __attribute__((ext_vector_type(4)));

// ---------------------------------------------------------------------------
// Fused 2-layer conv projection: conv3x3(1->8)+BN+ReLU, conv3x3(8->1)+BN+ReLU.
// 32x32 output tile per block; y1 (34x34x8) lives in LDS only.
// nparts==8: input is sum of 8 partial buffers (ctx reduction fused here).
// proj==2 (V): output is written TRANSPOSED as separate hi/lo bf16 buffers
// Vt[b][d][l] (for MFMA B-fragments in the attention kernel); no fp32 V.
// ---------------------------------------------------------------------------
__global__ __launch_bounds__(256)
void conv_proj_kernel(const float* __restrict__ in, int nparts,
                      float* __restrict__ out, int fixed_proj,
                      const float* __restrict__ w1, const float* __restrict__ b1,
                      const float* __restrict__ g1, const float* __restrict__ be1,
                      const float* __restrict__ m1, const float* __restrict__ v1,
                      const float* __restrict__ w2, const float* __restrict__ b2,
                      const float* __restrict__ g2, const float* __restrict__ be2,
                      const float* __restrict__ m2, const float* __restrict__ v2,
                      ushort* __restrict__ vth, ushort* __restrict__ vtl)
{
  __shared__ float xs[36][36];
  __shared__ float ys[8][34][34];
  __shared__ float w1s[8][9];
  __shared__ float w2s[8][9];
  __shared__ float a1s[8], c1s[8];
  __shared__ float a2s[1], c2s[1];

  const int t = threadIdx.x;
  int proj, b;
  if (fixed_proj < 0) { proj = blockIdx.z >> 2; b = blockIdx.z & 3; }
  else                { proj = fixed_proj;      b = blockIdx.z;     }
  const int h0 = blockIdx.y * 32;
  const int w0 = blockIdx.x * 32;

  if (t < 72) {
    w1s[t / 9][t % 9] = w1[proj * 72 + t];
    w2s[t / 9][t % 9] = w2[proj * 72 + t];
  } else if (t < 80) {
    int ch = t - 72;
    float a = g1[proj * 8 + ch] * rsqrtf(v1[proj * 8 + ch] + 1e-5f);
    a1s[ch] = a;
    c1s[ch] = fmaf(a, b1[proj * 8 + ch] - m1[proj * 8 + ch], be1[proj * 8 + ch]);
  } else if (t == 80) {
    float a = g2[proj] * rsqrtf(v2[proj] + 1e-5f);
    a2s[0] = a;
    c2s[0] = fmaf(a, b2[proj] - m2[proj], be2[proj]);
  }

  for (int idx = t; idx < 36 * 36; idx += 256) {
    int r = idx / 36, c = idx - r * 36;
    int hg = h0 - 2 + r, wg = w0 - 2 + c;
    float val = 0.f;
    if (hg >= 0 && hg < 512 && wg >= 0 && wg < 512) {
      int off = b * 262144 + hg * 512 + wg;
      if (nparts == 1) {
        val = in[off];
      } else {
        #pragma unroll
        for (int p = 0; p < 8; ++p) val += in[p * 1048576 + off];
      }
    }
    xs[r][c] = val;
  }
  __syncthreads();

  for (int idx = t; idx < 34 * 34; idx += 256) {
    int r = idx / 34, c = idx - r * 34;
    int hg1 = h0 - 1 + r, wg1 = w0 - 1 + c;
    bool inside = (hg1 >= 0) & (hg1 < 512) & (wg1 >= 0) & (wg1 < 512);
    float x0 = xs[r    ][c], x1 = xs[r    ][c + 1], x2 = xs[r    ][c + 2];
    float x3 = xs[r + 1][c], x4 = xs[r + 1][c + 1], x5 = xs[r + 1][c + 2];
    float x6 = xs[r + 2][c], x7 = xs[r + 2][c + 1], x8 = xs[r + 2][c + 2];
    #pragma unroll
    for (int ch = 0; ch < 8; ++ch) {
      const float* w = w1s[ch];
      float acc = w[0] * x0 + w[1] * x1 + w[2] * x2
                + w[3] * x3 + w[4] * x4 + w[5] * x5
                + w[6] * x6 + w[7] * x7 + w[8] * x8;
      float y = fmaxf(fmaf(acc, a1s[ch], c1s[ch]), 0.f);
      ys[ch][r][c] = inside ? y : 0.f;
    }
  }
  __syncthreads();

  const int r0 = (t >> 4) * 2;
  const int c0 = (t & 15) * 2;
  float o00 = 0.f, o01 = 0.f, o10 = 0.f, o11 = 0.f;
  #pragma unroll
  for (int ch = 0; ch < 8; ++ch) {
    float win[4][4];
    #pragma unroll
    for (int rr = 0; rr < 4; ++rr) {
      float2 p0 = *(const float2*)&ys[ch][r0 + rr][c0];
      float2 p1 = *(const float2*)&ys[ch][r0 + rr][c0 + 2];
      win[rr][0] = p0.x; win[rr][1] = p0.y; win[rr][2] = p1.x; win[rr][3] = p1.y;
    }
    #pragma unroll
    for (int dh = 0; dh < 3; ++dh)
      #pragma unroll
      for (int dw = 0; dw < 3; ++dw) {
        float wgt = w2s[ch][dh * 3 + dw];
        o00 = fmaf(wgt, win[dh    ][dw    ], o00);
        o01 = fmaf(wgt, win[dh    ][dw + 1], o01);
        o10 = fmaf(wgt, win[dh + 1][dw    ], o10);
        o11 = fmaf(wgt, win[dh + 1][dw + 1], o11);
      }
  }
  const float a2 = a2s[0], cc2 = c2s[0];
  float v00 = fmaxf(fmaf(o00, a2, cc2), 0.f);
  float v01 = fmaxf(fmaf(o01, a2, cc2), 0.f);
  float v10 = fmaxf(fmaf(o10, a2, cc2), 0.f);
  float v11 = fmaxf(fmaf(o11, a2, cc2), 0.f);

  const bool is_v = (fixed_proj < 0) && (proj == 2);
  if (!is_v) {
    const int sel = (fixed_proj < 0) ? proj : 0;
    float* ob = out + sel * 1048576 + b * 262144;
    *(float2*)&ob[(h0 + r0    ) * 512 + (w0 + c0)] = make_float2(v00, v01);
    *(float2*)&ob[(h0 + r0 + 1) * 512 + (w0 + c0)] = make_float2(v10, v11);
  } else {
    // Transpose 32x32 tile in LDS (xs is dead), then split-bf16 store of
    // Vt[b][d = w0+dl][l = h0+ll..+3], coalesced 8-B per lane.
    float* xf = &xs[0][0];                    // reused as [32][33]
    xf[(r0    ) * 33 + c0    ] = v00;
    xf[(r0    ) * 33 + c0 + 1] = v01;
    xf[(r0 + 1) * 33 + c0    ] = v10;
    xf[(r0 + 1) * 33 + c0 + 1] = v11;
    __syncthreads();
    const int dl = t >> 3;                    // 0..31 (feature d)
    const int ll = (t & 7) * 4;               // 0..28 (token l)
    uint hb[4], lb[4];
    #pragma unroll
    for (int k = 0; k < 4; ++k) {
      float x = xf[(ll + k) * 33 + dl];
      uint u = __float_as_uint(x);
      hb[k] = u >> 16;                        // truncation hi
      float r = x - __uint_as_float(u & 0xFFFF0000u);
      lb[k] = __float_as_uint(r) >> 16;       // truncation lo of residual
    }
    uint2 hv = make_uint2(hb[0] | (hb[1] << 16), hb[2] | (hb[3] << 16));
    uint2 lv = make_uint2(lb[0] | (lb[1] << 16), lb[2] | (lb[3] << 16));
    size_t off = (size_t)b * 262144 + (size_t)(w0 + dl) * 512 + (h0 + ll);
    *(uint2*)(vth + off) = hv;
    *(uint2*)(vtl + off) = lv;
  }
}

// ---------------------------------------------------------------------------
// Fused attention: scores + softmax + attn write + P@V_j -> ctxp.
// Block = (m-tile of 32 queries, (i,j) head pair, b). 256 threads / 4 waves.
// Score phase: fp32 VALU (unchanged this round), S 32x512 in registers.
// PV phase: MFMA 16x16x32 bf16, split hi/lo (Ph*Vh + Ph*Vl + Pl*Vh), fp32
// accumulate -> ~2^-16 relative error. P re-packed from softmax registers
// into XOR-swizzled LDS ([32][128] bf16, byte ^= (row&7)<<4); V chunks staged
// from the pre-transposed Vt hi/lo buffers. Per chunk: 24 frag ds_read_b128
// + 24 MFMA per wave, vs 192 ds_read_b128 + 1024 FMA for the fp32 path.
// LDS: score 42.5 KB / PV 48 KB (union, aliased) -> 3 blocks/CU.
// ---------------------------------------------------------------------------
__global__ __launch_bounds__(256)
void attn_fused_kernel(const float* __restrict__ Q, const float* __restrict__ K,
                       const ushort* __restrict__ vth, const ushort* __restrict__ vtl,
                       float* __restrict__ attn, float* __restrict__ ctxp)
{
  __shared__ __align__(16) float smem[12288];
  float* qs = smem;          // [32][68]   score phase
  float* kt = smem + 2176;   // [64][132]  score phase
  ushort* Ph = (ushort*)smem;            // [32][128] swizzled, PV phase
  ushort* Pl = (ushort*)(smem + 2048);
  ushort* Vh = (ushort*)(smem + 4096);   // [64][128] swizzled
  ushort* Vl = (ushort*)(smem + 8192);

  const int t  = threadIdx.x;
  const int b  = blockIdx.z;
  const int ij = blockIdx.y;
  const int i  = ij >> 3, j = ij & 7;
  const int m0 = blockIdx.x * 32;

  const int tm = t >> 5;    // 0..7: rows tm + 8*mm
  const int tn = t & 31;    // 0..31: cols tn*4 within each 128-chunk

  // Stage Q tile (32x64), scaled by 1/sqrt(64).
  {
    int m = t >> 3, d0 = (t & 7) * 8;
    const float* qp = &Q[b * 262144 + (m0 + m) * 512 + i * 64 + d0];
    float4 qa = *(const float4*)qp;
    float4 qb = *(const float4*)(qp + 4);
    *(float4*)&qs[m * 68 + d0] =
        make_float4(qa.x * 0.125f, qa.y * 0.125f, qa.z * 0.125f, qa.w * 0.125f);
    *(float4*)&qs[m * 68 + d0 + 4] =
        make_float4(qb.x * 0.125f, qb.y * 0.125f, qb.z * 0.125f, qb.w * 0.125f);
  }

  float S[4][4][4];  // [chunk][row mm][col nn] — static indexing (unrolled)

  #pragma unroll
  for (int c = 0; c < 4; ++c) {
    __syncthreads();
    // Stage K chunk transposed: kt[d][n], n = c*128..c*128+127, d = 0..63.
    {
      int n = t >> 1, d0 = (t & 1) * 32;
      const float* kp = &K[b * 262144 + (c * 128 + n) * 512 + j * 64 + d0];
      #pragma unroll
      for (int q4 = 0; q4 < 8; ++q4) {
        float4 kv = *(const float4*)&kp[q4 * 4];
        kt[(d0 + q4 * 4 + 0) * 132 + n] = kv.x;
        kt[(d0 + q4 * 4 + 1) * 132 + n] = kv.y;
        kt[(d0 + q4 * 4 + 2) * 132 + n] = kv.z;
        kt[(d0 + q4 * 4 + 3) * 132 + n] = kv.w;
      }
    }
    __syncthreads();
    #pragma unroll
    for (int mm = 0; mm < 4; ++mm)
      #pragma unroll
      for (int nn = 0; nn < 4; ++nn) S[c][mm][nn] = 0.f;
    #pragma unroll 2
    for (int dd = 0; dd < 64; dd += 4) {
      float4 k0 = *(const float4*)&kt[(dd + 0) * 132 + tn * 4];
      float4 k1 = *(const float4*)&kt[(dd + 1) * 132 + tn * 4];
      float4 k2 = *(const float4*)&kt[(dd + 2) * 132 + tn * 4];
      float4 k3 = *(const float4*)&kt[(dd + 3) * 132 + tn * 4];
      #pragma unroll
      for (int mm = 0; mm < 4; ++mm) {
        float4 qv = *(const float4*)&qs[(tm + 8 * mm) * 68 + dd];
        S[c][mm][0] = fmaf(qv.x, k0.x, fmaf(qv.y, k1.x, fmaf(qv.z, k2.x, fmaf(qv.w, k3.x, S[c][mm][0]))));
        S[c][mm][1] = fmaf(qv.x, k0.y, fmaf(qv.y, k1.y, fmaf(qv.z, k2.y, fmaf(qv.w, k3.y, S[c][mm][1]))));
        S[c][mm][2] = fmaf(qv.x, k0.z, fmaf(qv.y, k1.z, fmaf(qv.z, k2.z, fmaf(qv.w, k3.z, S[c][mm][2]))));
        S[c][mm][3] = fmaf(qv.x, k0.w, fmaf(qv.y, k1.w, fmaf(qv.z, k2.w, fmaf(qv.w, k3.w, S[c][mm][3]))));
      }
    }
  }

  // Softmax per row (512 keys spread over the 32-lane tn group), write attn.
  // wave64: xor offsets 1..16 stay within each 32-lane half = the tn group.
  float* ap = attn + (size_t)((b * 8 + i) * 8 + j) * 262144;
  #pragma unroll
  for (int mm = 0; mm < 4; ++mm) {
    float mx = -3.0e38f;
    #pragma unroll
    for (int c = 0; c < 4; ++c)
      #pragma unroll
      for (int nn = 0; nn < 4; ++nn) mx = fmaxf(mx, S[c][mm][nn]);
    #pragma unroll
    for (int off = 1; off < 32; off <<= 1) mx = fmaxf(mx, __shfl_xor(mx, off));
    float sum = 0.f;
    #pragma unroll
    for (int c = 0; c < 4; ++c)
      #pragma unroll
      for (int nn = 0; nn < 4; ++nn) {
        float e = __expf(S[c][mm][nn] - mx);
        S[c][mm][nn] = e;
        sum += e;
      }
    #pragma unroll
    for (int off = 1; off < 32; off <<= 1) sum += __shfl_xor(sum, off);
    float rinv = 1.0f / sum;
    float* rowp = ap + (size_t)(m0 + tm + 8 * mm) * 512;
    #pragma unroll
    for (int c = 0; c < 4; ++c) {
      float4 o = make_float4(S[c][mm][0] * rinv, S[c][mm][1] * rinv,
                             S[c][mm][2] * rinv, S[c][mm][3] * rinv);
      S[c][mm][0] = o.x; S[c][mm][1] = o.y; S[c][mm][2] = o.z; S[c][mm][3] = o.w;
      *(float4*)&rowp[c * 128 + tn * 4] = o;
    }
  }

  // -------------------- PV phase: MFMA split-bf16 --------------------
  // Wave w: q-group q0 = (w&1)*16 (rows q0..q0+15), d-tiles d0, d0+16 with
  // d0 = (w>>1)*32. A = P[16q][32k] frag: lane holds 8 contiguous bf16 at
  // [q0 + (lane&15)][ks*32 + (lane>>4)*8]. B = Vt[d][k] same pattern.
  // C: row(q) = (lane>>4)*4 + reg, col(d) = lane&15  [m89-verified].
  const int lane = t & 63;
  const int w    = t >> 6;
  const int q0   = (w & 1) * 16;
  const int d0   = (w >> 1) * 32;
  const int frow = lane & 15;
  const int kgrp = lane >> 4;              // 0..3
  f32x4 acc0 = {0.f, 0.f, 0.f, 0.f};
  f32x4 acc1 = {0.f, 0.f, 0.f, 0.f};

  const ushort* vhg = vth + (size_t)b * 262144 + (size_t)(j * 64) * 512;
  const ushort* vlg = vtl + (size_t)b * 262144 + (size_t)(j * 64) * 512;

  for (int c = 0; c < 4; ++c) {
    __syncthreads();   // previous chunk's frag reads (and score-phase LDS) done
    // P staging: thread holds P[tm+8mm][c*128 + tn*4 .. +3]; split hi/lo,
    // pack 4 bf16 -> uint2, swizzled ds_write_b64.
    #pragma unroll
    for (int mm = 0; mm < 4; ++mm) {
      int row = tm + 8 * mm;
      uint hb[4], lb[4];
      #pragma unroll
      for (int nn = 0; nn < 4; ++nn) {
        float x = S[c][mm][nn];
        uint u = __float_as_uint(x);
        hb[nn] = u >> 16;
        float r = x - __uint_as_float(u & 0xFFFF0000u);
        lb[nn] = __float_as_uint(r) >> 16;
      }
      uint2 hv = make_uint2(hb[0] | (hb[1] << 16), hb[2] | (hb[3] << 16));
      uint2 lv = make_uint2(lb[0] | (lb[1] << 16), lb[2] | (lb[3] << 16));
      int bo = (row * 256 + tn * 8) ^ ((row & 7) << 4);
      *(uint2*)((char*)Ph + bo) = hv;
      *(uint2*)((char*)Pl + bo) = lv;
    }
    // V staging: thread t stages Vt rows d = t>>2, l = c*128 + (t&3)*32 ..+31
    // (hi and lo), 16-B units, swizzled.
    {
      int d = t >> 2, l0 = (t & 3) * 32;
      const ushort* sh = vhg + (size_t)d * 512 + c * 128 + l0;
      const ushort* sl = vlg + (size_t)d * 512 + c * 128 + l0;
      #pragma unroll
      for (int q = 0; q < 4; ++q) {
        uint4 hv4 = *(const uint4*)(sh + q * 8);
        uint4 lv4 = *(const uint4*)(sl + q * 8);
        int bo = (d * 256 + l0 * 2 + q * 16) ^ ((d & 7) << 4);
        *(uint4*)((char*)Vh + bo) = hv4;
        *(uint4*)((char*)Vl + bo) = lv4;
      }
    }
    __syncthreads();
    // 4 k-steps x (2 d-tiles) x 3 split products = 24 MFMA per wave per chunk.
    #pragma unroll
    for (int ks = 0; ks < 4; ++ks) {
      int ka = ks * 64 + kgrp * 16;  // byte offset of k within a row
      int ao  = ((q0 + frow) * 256 + ka) ^ ((frow & 7) << 4);
      int bo0 = ((d0 + frow) * 256 + ka) ^ ((frow & 7) << 4);
      int bo1 = ((d0 + 16 + frow) * 256 + ka) ^ ((frow & 7) << 4);
      bf16x8 ah  = __builtin_bit_cast(bf16x8, *(const uint4*)((const char*)Ph + ao));
      bf16x8 al  = __builtin_bit_cast(bf16x8, *(const uint4*)((const char*)Pl + ao));
      bf16x8 bh0 = __builtin_bit_cast(bf16x8, *(const uint4*)((const char*)Vh + bo0));
      bf16x8 bl0 = __builtin_bit_cast(bf16x8, *(const uint4*)((const char*)Vl + bo0));
      bf16x8 bh1 = __builtin_bit_cast(bf16x8, *(const uint4*)((const char*)Vh + bo1));
      bf16x8 bl1 = __builtin_bit_cast(bf16x8, *(const uint4*)((const char*)Vl + bo1));
      acc0 = __builtin_amdgcn_mfma_f32_16x16x32_bf16(ah, bh0, acc0, 0, 0, 0);
      acc1 = __builtin_amdgcn_mfma_f32_16x16x32_bf16(ah, bh1, acc1, 0, 0, 0);
      acc0 = __builtin_amdgcn_mfma_f32_16x16x32_bf16(ah, bl0, acc0, 0, 0, 0);
      acc1 = __builtin_amdgcn_mfma_f32_16x16x32_bf16(ah, bl1, acc1, 0, 0, 0);
      acc0 = __builtin_amdgcn_mfma_f32_16x16x32_bf16(al, bh0, acc0, 0, 0, 0);
      acc1 = __builtin_amdgcn_mfma_f32_16x16x32_bf16(al, bh1, acc1, 0, 0, 0);
    }
  }

  // ctx partial write: C-layout row = kgrp*4 + reg, col = lane&15.
  float* op = ctxp + j * 1048576 + b * 262144 + i * 64;
  const int qbase = m0 + q0 + kgrp * 4;
  #pragma unroll
  for (int r = 0; r < 4; ++r) {
    op[(size_t)(qbase + r) * 512 + d0 + frow]      = acc0[r];
    op[(size_t)(qbase + r) * 512 + d0 + 16 + frow] = acc1[r];
  }
}

extern "C" void kernel_launch(void* const* d_in, const int* in_sizes, int n_in,
                              void* d_out, int out_size, void* d_ws, size_t ws_size,
                              hipStream_t stream)
{
  const float* X   = (const float*)d_in[0];
  // d_in[1] = valid_lens: unused by the reference computation.
  const float* w1  = (const float*)d_in[2];
  const float* b1  = (const float*)d_in[3];
  const float* g1  = (const float*)d_in[4];
  const float* be1 = (const float*)d_in[5];
  const float* m1  = (const float*)d_in[6];
  const float* v1  = (const float*)d_in[7];
  const float* w2  = (const float*)d_in[8];
  const float* b2  = (const float*)d_in[9];
  const float* g2  = (const float*)d_in[10];
  const float* be2 = (const float*)d_in[11];
  const float* m2  = (const float*)d_in[12];
  const float* v2  = (const float*)d_in[13];

  float* ws   = (float*)d_ws;
  float* Qb   = ws;                        // 1M floats
  float* Kb   = ws + 1048576;              // 1M floats
  ushort* Vth = (ushort*)(ws + 2097152);   // [4][512][512] bf16 hi (2 MB)
  ushort* Vtl = (ushort*)(ws + 2621440);   // [4][512][512] bf16 lo (2 MB)
  float* ctxp = ws + 3145728;              // 8 x 1M partials
  float* outp = (float*)d_out;             // out: 1,048,576 floats
  float* attn = outp + 1048576;            // attn: 67,108,864 floats

  // Q,K,V projections (proj 0..2 x b 0..3 in grid.z). V -> transposed bf16 hi/lo.
  conv_proj_kernel<<<dim3(16, 16, 12), 256, 0, stream>>>(
      X, 1, ws, -1, w1, b1, g1, be1, m1, v1, w2, b2, g2, be2, m2, v2, Vth, Vtl);

  // Fused scores + softmax + attn write + P@V (MFMA) -> ctx partials (j-split).
  attn_fused_kernel<<<dim3(16, 64, 4), 256, 0, stream>>>(Qb, Kb, Vth, Vtl, attn, ctxp);

  // Output projection (sums the 8 ctx partials during input staging).
  conv_proj_kernel<<<dim3(16, 16, 4), 256, 0, stream>>>(
      ctxp, 8, outp, 3, w1, b1, g1, be1, m1, v1, w2, b2, g2, be2, m2, v2,
      nullptr, nullptr);
}